// Round 1
// baseline (488.306 us; speedup 1.0000x reference)
//
#include <hip/hip_runtime.h>
#include <math.h>

// ---------------------------------------------------------------------------
// K1: logits = x @ Wfc^T + bfc, then maxprob = 1/sum(exp(l - lmax)) per token.
// M = 16*784 = 12544 tokens, N = 200 classes, K = 768.  f32 VALU GEMM.
// Block: 256 threads, 16 tokens, all 224 (padded) classes in registers.
// Thread (ty in [0,8), tx in [0,32)): 2 tokens x 7 classes (n = tx + 32j).
// ---------------------------------------------------------------------------
__global__ __launch_bounds__(256) void k_maxprob(
    const float* __restrict__ x, const float* __restrict__ Wfc,
    const float* __restrict__ bfc, float* __restrict__ maxprob)
{
    __shared__ float XT[16][36];    // +4 pad: conflict-free
    __shared__ float WT[224][36];
    const int tid = threadIdx.x;
    const int ty = tid >> 5;        // 0..7
    const int tx = tid & 31;        // 0..31
    const int row0 = blockIdx.x * 16;

    float acc[2][7];
#pragma unroll
    for (int i = 0; i < 2; ++i)
#pragma unroll
        for (int j = 0; j < 7; ++j) acc[i][j] = 0.f;

    const int lr = tid >> 4;           // 0..15  (XT row)
    const int lc = (tid & 15) * 2;     // 0..30  (XT col, float2)
    const int wr = tid >> 3;           // 0..31  (WT row slice)
    const int wc = (tid & 7) * 4;      // 0..28  (WT col, float4)

    for (int kc = 0; kc < 768; kc += 32) {
        __syncthreads();
        {
            const float2 v = *(const float2*)&x[(size_t)(row0 + lr) * 768 + kc + lc];
            XT[lr][lc] = v.x; XT[lr][lc + 1] = v.y;
        }
#pragma unroll
        for (int it = 0; it < 7; ++it) {
            const int n = wr + 32 * it;
            float4 v = make_float4(0.f, 0.f, 0.f, 0.f);
            if (n < 200) v = *(const float4*)&Wfc[(size_t)n * 768 + kc + wc];
            *(float4*)&WT[n][wc] = v;
        }
        __syncthreads();
#pragma unroll
        for (int k4 = 0; k4 < 32; k4 += 4) {
            const float4 xa = *(const float4*)&XT[ty * 2 + 0][k4];
            const float4 xb = *(const float4*)&XT[ty * 2 + 1][k4];
#pragma unroll
            for (int j = 0; j < 7; ++j) {
                const float4 w = *(const float4*)&WT[tx + 32 * j][k4];
                acc[0][j] += xa.x * w.x + xa.y * w.y + xa.z * w.z + xa.w * w.w;
                acc[1][j] += xb.x * w.x + xb.y * w.y + xb.z * w.z + xb.w * w.w;
            }
        }
    }

#pragma unroll
    for (int i = 0; i < 2; ++i) {
        float lg[7];
        float m = -1e30f;
#pragma unroll
        for (int j = 0; j < 7; ++j) {
            const int n = tx + 32 * j;
            lg[j] = (n < 200) ? (acc[i][j] + bfc[n]) : -1e30f;
            m = fmaxf(m, lg[j]);
        }
#pragma unroll
        for (int s = 16; s; s >>= 1) m = fmaxf(m, __shfl_xor(m, s, 32));
        float se = 0.f;
#pragma unroll
        for (int j = 0; j < 7; ++j) {
            const int n = tx + 32 * j;
            if (n < 200) se += __expf(lg[j] - m);
        }
#pragma unroll
        for (int s = 16; s; s >>= 1) se += __shfl_xor(se, s, 32);
        if (tx == 0) maxprob[row0 + ty * 2 + i] = 1.0f / se;
    }
}

// ---------------------------------------------------------------------------
// K2: part_logits[b,p] = mask[b,p] * mean_{64}(unfold(maxprob_grid,8,3,pad2));
//     sel[b] = argmax_p (first-max tie-break, matching jnp.argmax).
// ---------------------------------------------------------------------------
__global__ void k_sel(const float* __restrict__ maxprob,
                      const float* __restrict__ mask, int* __restrict__ sel)
{
    __shared__ float mp[784];
    __shared__ float pl[81];
    const int b = blockIdx.x, tid = threadIdx.x;
    for (int i = tid; i < 784; i += blockDim.x) mp[i] = maxprob[b * 784 + i];
    __syncthreads();
    if (tid < 81) {
        const int pr = tid / 9, pc = tid % 9;
        float s = 0.f;
        for (int ki = 0; ki < 8; ++ki) {
            const int y = pr * 3 - 2 + ki;
            if (y < 0 || y >= 28) continue;
            for (int kj = 0; kj < 8; ++kj) {
                const int xx = pc * 3 - 2 + kj;
                if (xx < 0 || xx >= 28) continue;
                s += mp[y * 28 + xx];
            }
        }
        pl[tid] = mask[b * 81 + tid] * (s * (1.f / 64.f));
    }
    __syncthreads();
    if (tid == 0) {
        float best = pl[0]; int bi = 0;
        for (int i = 1; i < 81; ++i) if (pl[i] > best) { best = pl[i]; bi = i; }
        sel[b] = bi;
    }
}

// bilinear coefficient, jax.image.resize 'bilinear' (upsample to 8 or 224):
// src = (o+0.5)*in/out - 0.5, clamped (== edge-normalized triangle kernel)
__device__ __forceinline__ void rcoef8(int o, int n, int& f0, int& f1, float& w)
{
    float s = (o + 0.5f) * ((float)n * 0.125f) - 0.5f;
    s = fminf(fmaxf(s, 0.f), (float)(n - 1));
    f0 = (int)s;
    w = s - (float)f0;
    f1 = f0 + 1; if (f1 > n - 1) f1 = n - 1;
}

// ---------------------------------------------------------------------------
// K3a: gather the selected 8x8x768 feature window per batch; emit
//   Al = outl (direct), Am = resize6->8 of inner 6x6, As = resize4->8 of 4x4.
// Layout of A*: [16][64][768] f32 (row i = oy*8+ox, col = channel).
// grid = 16 b x 3 channel-chunks of 256; c = chunk*256 + tid.
// ---------------------------------------------------------------------------
__global__ __launch_bounds__(256) void k_build(
    const float* __restrict__ x, const int* __restrict__ sel,
    float* __restrict__ Al, float* __restrict__ Am, float* __restrict__ As)
{
    __shared__ float W8[64][256];   // 64 KB: [spatial pos][channel]
    const int b = blockIdx.x / 3;
    const int tid = threadIdx.x;
    const int c = (blockIdx.x % 3) * 256 + tid;
    const int s = sel[b];
    const int y0 = (s / 9) * 3 - 2, x0 = (s % 9) * 3 - 2;

#pragma unroll 4
    for (int p = 0; p < 64; ++p) {
        const int yy = y0 + (p >> 3), xx = x0 + (p & 7);
        float v = 0.f;
        if (yy >= 0 && yy < 28 && xx >= 0 && xx < 28)
            v = x[((size_t)b * 784 + yy * 28 + xx) * 768 + c];
        W8[p][tid] = v;
    }
    __syncthreads();

    // outl: direct copy of the 8x8 window
#pragma unroll 4
    for (int p = 0; p < 64; ++p)
        Al[((size_t)b * 64 + p) * 768 + c] = W8[p][tid];

    // outm: 6x6 grid at window offset (1,1) -> 8x8 bilinear
    {
        int f0[8], f1[8]; float w[8];
        for (int o = 0; o < 8; ++o) rcoef8(o, 6, f0[o], f1[o], w[o]);
        for (int oy = 0; oy < 8; ++oy)
            for (int ox = 0; ox < 8; ++ox) {
                const float g00 = W8[(1 + f0[oy]) * 8 + 1 + f0[ox]][tid];
                const float g01 = W8[(1 + f0[oy]) * 8 + 1 + f1[ox]][tid];
                const float g10 = W8[(1 + f1[oy]) * 8 + 1 + f0[ox]][tid];
                const float g11 = W8[(1 + f1[oy]) * 8 + 1 + f1[ox]][tid];
                const float v0 = g00 + w[ox] * (g01 - g00);
                const float v1 = g10 + w[ox] * (g11 - g10);
                Am[((size_t)b * 64 + oy * 8 + ox) * 768 + c] = v0 + w[oy] * (v1 - v0);
            }
    }
    // outs: 4x4 grid at window offset (2,2) -> 8x8 bilinear
    {
        int f0[8], f1[8]; float w[8];
        for (int o = 0; o < 8; ++o) rcoef8(o, 4, f0[o], f1[o], w[o]);
        for (int oy = 0; oy < 8; ++oy)
            for (int ox = 0; ox < 8; ++ox) {
                const float g00 = W8[(2 + f0[oy]) * 8 + 2 + f0[ox]][tid];
                const float g01 = W8[(2 + f0[oy]) * 8 + 2 + f1[ox]][tid];
                const float g10 = W8[(2 + f1[oy]) * 8 + 2 + f0[ox]][tid];
                const float g11 = W8[(2 + f1[oy]) * 8 + 2 + f1[ox]][tid];
                const float v0 = g00 + w[ox] * (g01 - g00);
                const float v1 = g10 + w[ox] * (g11 - g10);
                As[((size_t)b * 64 + oy * 8 + ox) * 768 + c] = v0 + w[oy] * (v1 - v0);
            }
    }
}

// ---------------------------------------------------------------------------
// K3b: ff_cat GEMM. out[b, i, n], n in [0,768): n<192: Al@Wl; n<384: Am@Wm;
// else As@Ws. grid = 16 b x 12 n-tiles of 64 (tile boundaries align with the
// segment boundaries). 256 threads, thread tile 4x4, K-chunks of 32 in LDS.
// ---------------------------------------------------------------------------
__global__ __launch_bounds__(256) void k_gemm(
    const float* __restrict__ Al, const float* __restrict__ Am, const float* __restrict__ As,
    const float* __restrict__ Wl, const float* __restrict__ bl,
    const float* __restrict__ Wm, const float* __restrict__ bm,
    const float* __restrict__ Ws, const float* __restrict__ bs_,
    float* __restrict__ out)
{
    __shared__ float At[64][36];
    __shared__ float Wt[64][36];
    const int blk = blockIdx.x;
    const int b = blk / 12, t = blk % 12;
    const float* A; const float* W; const float* bias;
    if (t < 3)      { A = Al; W = Wl + (size_t)t       * 64 * 768; bias = bl  + t * 64; }
    else if (t < 6) { A = Am; W = Wm + (size_t)(t - 3) * 64 * 768; bias = bm  + (t - 3) * 64; }
    else            { A = As; W = Ws + (size_t)(t - 6) * 64 * 768; bias = bs_ + (t - 6) * 64; }
    A += (size_t)b * 64 * 768;
    const int n0 = t * 64;
    const int tid = threadIdx.x;
    const int ti = tid >> 4, tn = tid & 15;
    const int lr = tid >> 2;            // 0..63
    const int lc = (tid & 3) * 8;       // 0,8,16,24

    float acc[4][4];
#pragma unroll
    for (int r = 0; r < 4; ++r)
#pragma unroll
        for (int q = 0; q < 4; ++q) acc[r][q] = 0.f;

    for (int kc = 0; kc < 768; kc += 32) {
        __syncthreads();
        *(float4*)&At[lr][lc]     = *(const float4*)&A[(size_t)lr * 768 + kc + lc];
        *(float4*)&At[lr][lc + 4] = *(const float4*)&A[(size_t)lr * 768 + kc + lc + 4];
        *(float4*)&Wt[lr][lc]     = *(const float4*)&W[(size_t)lr * 768 + kc + lc];
        *(float4*)&Wt[lr][lc + 4] = *(const float4*)&W[(size_t)lr * 768 + kc + lc + 4];
        __syncthreads();
#pragma unroll
        for (int k4 = 0; k4 < 32; k4 += 4) {
            float4 a[4], w[4];
#pragma unroll
            for (int r = 0; r < 4; ++r) a[r] = *(const float4*)&At[ti + 16 * r][k4];
#pragma unroll
            for (int q = 0; q < 4; ++q) w[q] = *(const float4*)&Wt[tn + 16 * q][k4];
#pragma unroll
            for (int r = 0; r < 4; ++r)
#pragma unroll
                for (int q = 0; q < 4; ++q)
                    acc[r][q] += a[r].x * w[q].x + a[r].y * w[q].y
                               + a[r].z * w[q].z + a[r].w * w[q].w;
        }
    }
#pragma unroll
    for (int r = 0; r < 4; ++r)
#pragma unroll
        for (int q = 0; q < 4; ++q)
            out[((size_t)b * 64 + ti + 16 * r) * 768 + n0 + tn + 16 * q]
                = acc[r][q] + bias[tn + 16 * q];
}

// ---------------------------------------------------------------------------
// K4: image_part. Gather selected 128x128 img patch (zero-padded coords) and
// bilinear-resize to 224x224. One output per thread; 2408448 outputs.
// ---------------------------------------------------------------------------
__global__ __launch_bounds__(256) void k_image(
    const float* __restrict__ img, const int* __restrict__ sel,
    float* __restrict__ out)
{
    const int idx = blockIdx.x * 256 + threadIdx.x;
    if (idx >= 16 * 3 * 224 * 224) return;
    const int ox = idx % 224;
    int t = idx / 224;
    const int oy = t % 224; t /= 224;
    const int c = t % 3;
    const int b = t / 3;
    const int s = sel[b];
    const int ry0 = (s / 9) * 48 - 32, cx0 = (s % 9) * 48 - 32;

    float sy = (oy + 0.5f) * (128.f / 224.f) - 0.5f;
    sy = fminf(fmaxf(sy, 0.f), 127.f);
    const int fy0 = (int)sy; const float wy = sy - (float)fy0;
    const int fy1 = (fy0 < 127) ? fy0 + 1 : 127;

    float sx = (ox + 0.5f) * (128.f / 224.f) - 0.5f;
    sx = fminf(fmaxf(sx, 0.f), 127.f);
    const int fx0 = (int)sx; const float wx = sx - (float)fx0;
    const int fx1 = (fx0 < 127) ? fx0 + 1 : 127;

    const float* ib = img + ((size_t)b * 3 + c) * 448 * 448;
    auto rd = [&](int py, int px) -> float {
        const int r = ry0 + py, cc = cx0 + px;
        return (r >= 0 && r < 448 && cc >= 0 && cc < 448) ? ib[r * 448 + cc] : 0.f;
    };
    const float g00 = rd(fy0, fx0), g01 = rd(fy0, fx1);
    const float g10 = rd(fy1, fx0), g11 = rd(fy1, fx1);
    const float v0 = g00 + wx * (g01 - g00);
    const float v1 = g10 + wx * (g11 - g10);
    out[idx] = v0 + wy * (v1 - v0);
}

// ---------------------------------------------------------------------------
extern "C" void kernel_launch(void* const* d_in, const int* in_sizes, int n_in,
                              void* d_out, int out_size, void* d_ws, size_t ws_size,
                              hipStream_t stream)
{
    const float* x    = (const float*)d_in[0];   // [16,784,768]
    const float* mask = (const float*)d_in[1];   // [16,81]
    const float* img  = (const float*)d_in[2];   // [16,3,448,448]
    const float* Wfc  = (const float*)d_in[3];   // [200,768]
    const float* bfc  = (const float*)d_in[4];   // [200]
    const float* Wl   = (const float*)d_in[5];   // [192,768]
    const float* bl   = (const float*)d_in[6];
    const float* Wm   = (const float*)d_in[7];   // [192,768]
    const float* bm   = (const float*)d_in[8];
    const float* Ws   = (const float*)d_in[9];   // [384,768]
    const float* bs   = (const float*)d_in[10];
    float* out = (float*)d_out;

    char* ws = (char*)d_ws;
    float* maxprob = (float*)ws;                       // 12544 f32
    int*   sel     = (int*)(ws + 51200);               // 16 ints
    float* Al      = (float*)(ws + 65536);             // [16][64][768]
    float* Am      = Al + (size_t)16 * 64 * 768;
    float* As      = Am + (size_t)16 * 64 * 768;

    hipLaunchKernelGGL(k_maxprob, dim3(784), dim3(256), 0, stream, x, Wfc, bfc, maxprob);
    hipLaunchKernelGGL(k_sel,     dim3(16),  dim3(128), 0, stream, maxprob, mask, sel);
    hipLaunchKernelGGL(k_build,   dim3(48),  dim3(256), 0, stream, x, sel, Al, Am, As);
    hipLaunchKernelGGL(k_gemm,    dim3(192), dim3(256), 0, stream,
                       Al, Am, As, Wl, bl, Wm, bm, Ws, bs, out);
    hipLaunchKernelGGL(k_image,   dim3(9408), dim3(256), 0, stream,
                       img, sel, out + 786432);
}

// Round 2
// 245.400 us; speedup vs baseline: 1.9898x; 1.9898x over previous
//
#include <hip/hip_runtime.h>
#include <math.h>

typedef __attribute__((ext_vector_type(8))) short bf16x8;
typedef __attribute__((ext_vector_type(4))) float f32x4;

__device__ __forceinline__ unsigned short f32_to_bf16_rne(float f) {
    unsigned int u = __float_as_uint(f);
    unsigned int r = (u + 0x7FFFu + ((u >> 16) & 1u)) >> 16;
    return (unsigned short)r;
}
__device__ __forceinline__ float bf16_to_f32(unsigned short h) {
    return __uint_as_float(((unsigned int)h) << 16);
}
__device__ __forceinline__ unsigned int pck(unsigned short a, unsigned short b) {
    return (unsigned int)a | ((unsigned int)b << 16);
}

// ---------------------------------------------------------------------------
// K0: split Wfc [200][768] f32 -> Whi/Wlo bf16 [256][768], rows >=200 zero.
// ---------------------------------------------------------------------------
__global__ __launch_bounds__(256) void k_wsplit(
    const float* __restrict__ Wfc, unsigned short* __restrict__ Whi,
    unsigned short* __restrict__ Wlo)
{
    const int idx = blockIdx.x * 256 + threadIdx.x;   // 49152 quads
    const int c = idx / 192;
    const int kk = (idx % 192) * 4;
    unsigned short h[4] = {0, 0, 0, 0}, l[4] = {0, 0, 0, 0};
    if (c < 200) {
        const float4 w = *(const float4*)&Wfc[c * 768 + kk];
        const float wv[4] = {w.x, w.y, w.z, w.w};
#pragma unroll
        for (int j = 0; j < 4; ++j) {
            h[j] = f32_to_bf16_rne(wv[j]);
            l[j] = f32_to_bf16_rne(wv[j] - bf16_to_f32(h[j]));
        }
    }
    *(uint2*)&Whi[c * 768 + kk] = make_uint2(pck(h[0], h[1]), pck(h[2], h[3]));
    *(uint2*)&Wlo[c * 768 + kk] = make_uint2(pck(l[0], l[1]), pck(l[2], l[3]));
}

// ---------------------------------------------------------------------------
// K1: logits[12544][256] = x @ W^T via bf16-split MFMA (hi*hi + hi*lo + lo*hi).
// BM=64, BN=128, BK=32; 4 waves (2M x 2N); wave tile 32x64 (2x4 frags).
// LDS frag-major: [frag][lane][8 shorts] so ds_read_b128 is conflict-free.
// mfma_f32_16x16x32_bf16: A lane: row=l&15,k=(l>>4)*8+j; B lane: col=l&15,
// k=(l>>4)*8+j; D lane: row=(l>>4)*4+r, col=l&15  (m89-verified layout).
// ---------------------------------------------------------------------------
__global__ __launch_bounds__(256) void k_logits(
    const float* __restrict__ x, const unsigned short* __restrict__ Whi,
    const unsigned short* __restrict__ Wlo, float* __restrict__ logits)
{
    __shared__ unsigned short Ah[4][64][8], Alo[4][64][8];   // 8 KB
    __shared__ unsigned short Bh[8][64][8], Blo[8][64][8];   // 16 KB
    const int tid = threadIdx.x;
    const int lane = tid & 63;
    const int wid = tid >> 6;
    const int wm = wid & 1, wn = wid >> 1;
    const int row0 = blockIdx.x * 64;
    const int n0 = blockIdx.y * 128;

    f32x4 acc[2][4];
    const f32x4 z = {0.f, 0.f, 0.f, 0.f};
#pragma unroll
    for (int mi = 0; mi < 2; ++mi)
#pragma unroll
        for (int q = 0; q < 4; ++q) acc[mi][q] = z;

    const int ar = tid & 63;       // A: row within tile
    const int ap = tid >> 6;       // A: k-octet 0..3
    const int bc = tid >> 1;       // B: class within tile 0..127
    const int bkh = tid & 1;       // B: k-half 0..1

    for (int kc = 0; kc < 768; kc += 32) {
        __syncthreads();
        {   // A stage + on-the-fly bf16 split
            const float* src = &x[(size_t)(row0 + ar) * 768 + kc + ap * 8];
            const float4 v0 = *(const float4*)src;
            const float4 v1 = *(const float4*)(src + 4);
            const float av[8] = {v0.x, v0.y, v0.z, v0.w, v1.x, v1.y, v1.z, v1.w};
            unsigned short h[8], l[8];
#pragma unroll
            for (int j = 0; j < 8; ++j) {
                h[j] = f32_to_bf16_rne(av[j]);
                l[j] = f32_to_bf16_rne(av[j] - bf16_to_f32(h[j]));
            }
            const int m = ar >> 4, ci = ar & 15;
            *(uint4*)&Ah[m][ap * 16 + ci][0] =
                make_uint4(pck(h[0], h[1]), pck(h[2], h[3]), pck(h[4], h[5]), pck(h[6], h[7]));
            *(uint4*)&Alo[m][ap * 16 + ci][0] =
                make_uint4(pck(l[0], l[1]), pck(l[2], l[3]), pck(l[4], l[5]), pck(l[6], l[7]));
        }
        {   // B stage (already bf16): 1 class x 16 k per thread
            const size_t off = (size_t)(n0 + bc) * 768 + kc + bkh * 16;
            const uint4 h0 = *(const uint4*)&Whi[off];
            const uint4 h1 = *(const uint4*)&Whi[off + 8];
            const uint4 l0 = *(const uint4*)&Wlo[off];
            const uint4 l1 = *(const uint4*)&Wlo[off + 8];
            const int q = bc >> 4, ci = bc & 15;
            *(uint4*)&Bh[q][(2 * bkh) * 16 + ci][0] = h0;
            *(uint4*)&Bh[q][(2 * bkh + 1) * 16 + ci][0] = h1;
            *(uint4*)&Blo[q][(2 * bkh) * 16 + ci][0] = l0;
            *(uint4*)&Blo[q][(2 * bkh + 1) * 16 + ci][0] = l1;
        }
        __syncthreads();

        bf16x8 a_h[2], a_l[2];
#pragma unroll
        for (int mi = 0; mi < 2; ++mi) {
            a_h[mi] = *(const bf16x8*)&Ah[wm * 2 + mi][lane][0];
            a_l[mi] = *(const bf16x8*)&Alo[wm * 2 + mi][lane][0];
        }
#pragma unroll
        for (int q = 0; q < 4; ++q) {
            const bf16x8 bh = *(const bf16x8*)&Bh[wn * 4 + q][lane][0];
            const bf16x8 bl = *(const bf16x8*)&Blo[wn * 4 + q][lane][0];
#pragma unroll
            for (int mi = 0; mi < 2; ++mi) {
                acc[mi][q] = __builtin_amdgcn_mfma_f32_16x16x32_bf16(a_l[mi], bh, acc[mi][q], 0, 0, 0);
                acc[mi][q] = __builtin_amdgcn_mfma_f32_16x16x32_bf16(a_h[mi], bl, acc[mi][q], 0, 0, 0);
                acc[mi][q] = __builtin_amdgcn_mfma_f32_16x16x32_bf16(a_h[mi], bh, acc[mi][q], 0, 0, 0);
            }
        }
    }

#pragma unroll
    for (int mi = 0; mi < 2; ++mi)
#pragma unroll
        for (int q = 0; q < 4; ++q)
#pragma unroll
            for (int r = 0; r < 4; ++r) {
                const int row = row0 + wm * 32 + mi * 16 + (lane >> 4) * 4 + r;
                const int col = n0 + wn * 64 + q * 16 + (lane & 15);
                logits[(size_t)row * 256 + col] = acc[mi][q][r];
            }
}

// ---------------------------------------------------------------------------
// K1b: maxprob[row] = 1 / sum(exp(logit - max)). One wave per row.
// ---------------------------------------------------------------------------
__global__ __launch_bounds__(256) void k_softmax(
    const float* __restrict__ logits, const float* __restrict__ bfc,
    float* __restrict__ maxprob)
{
    const int row = blockIdx.x * 4 + (threadIdx.x >> 6);
    const int lane = threadIdx.x & 63;
    float v[4];
    float m = -1e30f;
#pragma unroll
    for (int j = 0; j < 4; ++j) {
        const int c = lane + j * 64;
        v[j] = (c < 200) ? (logits[(size_t)row * 256 + c] + bfc[c]) : -1e30f;
        m = fmaxf(m, v[j]);
    }
#pragma unroll
    for (int s = 32; s; s >>= 1) m = fmaxf(m, __shfl_xor(m, s, 64));
    float se = 0.f;
#pragma unroll
    for (int j = 0; j < 4; ++j) {
        const int c = lane + j * 64;
        if (c < 200) se += __expf(v[j] - m);
    }
#pragma unroll
    for (int s = 32; s; s >>= 1) se += __shfl_xor(se, s, 64);
    if (lane == 0) maxprob[row] = 1.0f / se;
}

// ---------------------------------------------------------------------------
// K2: part_logits + argmax -> sel  (unchanged, correct in round 1)
// ---------------------------------------------------------------------------
__global__ void k_sel(const float* __restrict__ maxprob,
                      const float* __restrict__ mask, int* __restrict__ sel)
{
    __shared__ float mp[784];
    __shared__ float pl[81];
    const int b = blockIdx.x, tid = threadIdx.x;
    for (int i = tid; i < 784; i += blockDim.x) mp[i] = maxprob[b * 784 + i];
    __syncthreads();
    if (tid < 81) {
        const int pr = tid / 9, pc = tid % 9;
        float s = 0.f;
        for (int ki = 0; ki < 8; ++ki) {
            const int y = pr * 3 - 2 + ki;
            if (y < 0 || y >= 28) continue;
            for (int kj = 0; kj < 8; ++kj) {
                const int xx = pc * 3 - 2 + kj;
                if (xx < 0 || xx >= 28) continue;
                s += mp[y * 28 + xx];
            }
        }
        pl[tid] = mask[b * 81 + tid] * (s * (1.f / 64.f));
    }
    __syncthreads();
    if (tid == 0) {
        float best = pl[0]; int bi = 0;
        for (int i = 1; i < 81; ++i) if (pl[i] > best) { best = pl[i]; bi = i; }
        sel[b] = bi;
    }
}

__device__ __forceinline__ void rcoef8(int o, int n, int& f0, int& f1, float& w)
{
    float s = (o + 0.5f) * ((float)n * 0.125f) - 0.5f;
    s = fminf(fmaxf(s, 0.f), (float)(n - 1));
    f0 = (int)s;
    w = s - (float)f0;
    f1 = f0 + 1; if (f1 > n - 1) f1 = n - 1;
}

// ---------------------------------------------------------------------------
// K3a: gather selected 8x8x768 window; emit Al / Am(6->8) / As(4->8). Unchanged.
// ---------------------------------------------------------------------------
__global__ __launch_bounds__(256) void k_build(
    const float* __restrict__ x, const int* __restrict__ sel,
    float* __restrict__ Al, float* __restrict__ Am, float* __restrict__ As)
{
    __shared__ float W8[64][256];
    const int b = blockIdx.x / 3;
    const int tid = threadIdx.x;
    const int c = (blockIdx.x % 3) * 256 + tid;
    const int s = sel[b];
    const int y0 = (s / 9) * 3 - 2, x0 = (s % 9) * 3 - 2;

#pragma unroll 4
    for (int p = 0; p < 64; ++p) {
        const int yy = y0 + (p >> 3), xx = x0 + (p & 7);
        float v = 0.f;
        if (yy >= 0 && yy < 28 && xx >= 0 && xx < 28)
            v = x[((size_t)b * 784 + yy * 28 + xx) * 768 + c];
        W8[p][tid] = v;
    }
    __syncthreads();

#pragma unroll 4
    for (int p = 0; p < 64; ++p)
        Al[((size_t)b * 64 + p) * 768 + c] = W8[p][tid];

    {
        int f0[8], f1[8]; float w[8];
        for (int o = 0; o < 8; ++o) rcoef8(o, 6, f0[o], f1[o], w[o]);
        for (int oy = 0; oy < 8; ++oy)
            for (int ox = 0; ox < 8; ++ox) {
                const float g00 = W8[(1 + f0[oy]) * 8 + 1 + f0[ox]][tid];
                const float g01 = W8[(1 + f0[oy]) * 8 + 1 + f1[ox]][tid];
                const float g10 = W8[(1 + f1[oy]) * 8 + 1 + f0[ox]][tid];
                const float g11 = W8[(1 + f1[oy]) * 8 + 1 + f1[ox]][tid];
                const float v0 = g00 + w[ox] * (g01 - g00);
                const float v1 = g10 + w[ox] * (g11 - g10);
                Am[((size_t)b * 64 + oy * 8 + ox) * 768 + c] = v0 + w[oy] * (v1 - v0);
            }
    }
    {
        int f0[8], f1[8]; float w[8];
        for (int o = 0; o < 8; ++o) rcoef8(o, 4, f0[o], f1[o], w[o]);
        for (int oy = 0; oy < 8; ++oy)
            for (int ox = 0; ox < 8; ++ox) {
                const float g00 = W8[(2 + f0[oy]) * 8 + 2 + f0[ox]][tid];
                const float g01 = W8[(2 + f0[oy]) * 8 + 2 + f1[ox]][tid];
                const float g10 = W8[(2 + f1[oy]) * 8 + 2 + f0[ox]][tid];
                const float g11 = W8[(2 + f1[oy]) * 8 + 2 + f1[ox]][tid];
                const float v0 = g00 + w[ox] * (g01 - g00);
                const float v1 = g10 + w[ox] * (g11 - g10);
                As[((size_t)b * 64 + oy * 8 + ox) * 768 + c] = v0 + w[oy] * (v1 - v0);
            }
    }
}

// ---------------------------------------------------------------------------
// K3b: ff_cat GEMM (f32 VALU, unchanged — next round's target).
// ---------------------------------------------------------------------------
__global__ __launch_bounds__(256) void k_gemm(
    const float* __restrict__ Al, const float* __restrict__ Am, const float* __restrict__ As,
    const float* __restrict__ Wl, const float* __restrict__ bl,
    const float* __restrict__ Wm, const float* __restrict__ bm,
    const float* __restrict__ Ws, const float* __restrict__ bs_,
    float* __restrict__ out)
{
    __shared__ float At[64][36];
    __shared__ float Wt[64][36];
    const int blk = blockIdx.x;
    const int b = blk / 12, t = blk % 12;
    const float* A; const float* W; const float* bias;
    if (t < 3)      { A = Al; W = Wl + (size_t)t       * 64 * 768; bias = bl  + t * 64; }
    else if (t < 6) { A = Am; W = Wm + (size_t)(t - 3) * 64 * 768; bias = bm  + (t - 3) * 64; }
    else            { A = As; W = Ws + (size_t)(t - 6) * 64 * 768; bias = bs_ + (t - 6) * 64; }
    A += (size_t)b * 64 * 768;
    const int n0 = t * 64;
    const int tid = threadIdx.x;
    const int ti = tid >> 4, tn = tid & 15;
    const int lr = tid >> 2;
    const int lc = (tid & 3) * 8;

    float acc[4][4];
#pragma unroll
    for (int r = 0; r < 4; ++r)
#pragma unroll
        for (int q = 0; q < 4; ++q) acc[r][q] = 0.f;

    for (int kc = 0; kc < 768; kc += 32) {
        __syncthreads();
        *(float4*)&At[lr][lc]     = *(const float4*)&A[(size_t)lr * 768 + kc + lc];
        *(float4*)&At[lr][lc + 4] = *(const float4*)&A[(size_t)lr * 768 + kc + lc + 4];
        *(float4*)&Wt[lr][lc]     = *(const float4*)&W[(size_t)lr * 768 + kc + lc];
        *(float4*)&Wt[lr][lc + 4] = *(const float4*)&W[(size_t)lr * 768 + kc + lc + 4];
        __syncthreads();
#pragma unroll
        for (int k4 = 0; k4 < 32; k4 += 4) {
            float4 a[4], w[4];
#pragma unroll
            for (int r = 0; r < 4; ++r) a[r] = *(const float4*)&At[ti + 16 * r][k4];
#pragma unroll
            for (int q = 0; q < 4; ++q) w[q] = *(const float4*)&Wt[tn + 16 * q][k4];
#pragma unroll
            for (int r = 0; r < 4; ++r)
#pragma unroll
                for (int q = 0; q < 4; ++q)
                    acc[r][q] += a[r].x * w[q].x + a[r].y * w[q].y
                               + a[r].z * w[q].z + a[r].w * w[q].w;
        }
    }
#pragma unroll
    for (int r = 0; r < 4; ++r)
#pragma unroll
        for (int q = 0; q < 4; ++q)
            out[((size_t)b * 64 + ti + 16 * r) * 768 + n0 + tn + 16 * q]
                = acc[r][q] + bias[tn + 16 * q];
}

// ---------------------------------------------------------------------------
// K4: image_part gather + 128->224 bilinear. Unchanged.
// ---------------------------------------------------------------------------
__global__ __launch_bounds__(256) void k_image(
    const float* __restrict__ img, const int* __restrict__ sel,
    float* __restrict__ out)
{
    const int idx = blockIdx.x * 256 + threadIdx.x;
    if (idx >= 16 * 3 * 224 * 224) return;
    const int ox = idx % 224;
    int t = idx / 224;
    const int oy = t % 224; t /= 224;
    const int c = t % 3;
    const int b = t / 3;
    const int s = sel[b];
    const int ry0 = (s / 9) * 48 - 32, cx0 = (s % 9) * 48 - 32;

    float sy = (oy + 0.5f) * (128.f / 224.f) - 0.5f;
    sy = fminf(fmaxf(sy, 0.f), 127.f);
    const int fy0 = (int)sy; const float wy = sy - (float)fy0;
    const int fy1 = (fy0 < 127) ? fy0 + 1 : 127;

    float sx = (ox + 0.5f) * (128.f / 224.f) - 0.5f;
    sx = fminf(fmaxf(sx, 0.f), 127.f);
    const int fx0 = (int)sx; const float wx = sx - (float)fx0;
    const int fx1 = (fx0 < 127) ? fx0 + 1 : 127;

    const float* ib = img + ((size_t)b * 3 + c) * 448 * 448;
    auto rd = [&](int py, int px) -> float {
        const int r = ry0 + py, cc = cx0 + px;
        return (r >= 0 && r < 448 && cc >= 0 && cc < 448) ? ib[r * 448 + cc] : 0.f;
    };
    const float g00 = rd(fy0, fx0), g01 = rd(fy0, fx1);
    const float g10 = rd(fy1, fx0), g11 = rd(fy1, fx1);
    const float v0 = g00 + wx * (g01 - g00);
    const float v1 = g10 + wx * (g11 - g10);
    out[idx] = v0 + wy * (v1 - v0);
}

// ---------------------------------------------------------------------------
extern "C" void kernel_launch(void* const* d_in, const int* in_sizes, int n_in,
                              void* d_out, int out_size, void* d_ws, size_t ws_size,
                              hipStream_t stream)
{
    const float* x    = (const float*)d_in[0];
    const float* mask = (const float*)d_in[1];
    const float* img  = (const float*)d_in[2];
    const float* Wfc  = (const float*)d_in[3];
    const float* bfc  = (const float*)d_in[4];
    const float* Wl   = (const float*)d_in[5];
    const float* bl   = (const float*)d_in[6];
    const float* Wm   = (const float*)d_in[7];
    const float* bm   = (const float*)d_in[8];
    const float* Ws   = (const float*)d_in[9];
    const float* bs   = (const float*)d_in[10];
    float* out = (float*)d_out;

    char* ws = (char*)d_ws;
    float* maxprob        = (float*)ws;                    // 12544 f32
    int*   sel            = (int*)(ws + 51200);            // 16 ints
    unsigned short* Whi   = (unsigned short*)(ws + 65536); // 256*768 bf16
    unsigned short* Wlo   = (unsigned short*)(ws + 65536 + 393216);
    // big region @ 1 MB: logits [12544][256] f32 (12.85 MB), dead after
    // k_softmax; Al/Am/As overlap it afterwards (9.44 MB).
    float* logits = (float*)(ws + 1048576);
    float* Al     = (float*)(ws + 1048576);
    float* Am     = Al + (size_t)16 * 64 * 768;
    float* As     = Am + (size_t)16 * 64 * 768;

    hipLaunchKernelGGL(k_wsplit,  dim3(192),      dim3(256), 0, stream, Wfc, Whi, Wlo);
    hipLaunchKernelGGL(k_logits,  dim3(196, 2),   dim3(256), 0, stream, x, Whi, Wlo, logits);
    hipLaunchKernelGGL(k_softmax, dim3(3136),     dim3(256), 0, stream, logits, bfc, maxprob);
    hipLaunchKernelGGL(k_sel,     dim3(16),       dim3(128), 0, stream, maxprob, mask, sel);
    hipLaunchKernelGGL(k_build,   dim3(48),       dim3(256), 0, stream, x, sel, Al, Am, As);
    hipLaunchKernelGGL(k_gemm,    dim3(192),      dim3(256), 0, stream,
                       Al, Am, As, Wl, bl, Wm, bm, Ws, bs, out);
    hipLaunchKernelGGL(k_image,   dim3(9408),     dim3(256), 0, stream,
                       img, sel, out + 786432);
}

// Round 4
// 215.897 us; speedup vs baseline: 2.2618x; 1.1367x over previous
//
#include <hip/hip_runtime.h>
#include <math.h>

typedef __attribute__((ext_vector_type(8))) short bf16x8;
typedef __attribute__((ext_vector_type(4))) float f32x4;

__device__ __forceinline__ unsigned short f32_to_bf16_rne(float f) {
    unsigned int u = __float_as_uint(f);
    unsigned int r = (u + 0x7FFFu + ((u >> 16) & 1u)) >> 16;
    return (unsigned short)r;
}
__device__ __forceinline__ float bf16_to_f32(unsigned short h) {
    return __uint_as_float(((unsigned int)h) << 16);
}
__device__ __forceinline__ unsigned int pck(unsigned short a, unsigned short b) {
    return (unsigned int)a | ((unsigned int)b << 16);
}

// ---------------------------------------------------------------------------
// K0: generic f32 -> bf16 hi/lo row split. dst rows beyond src_rows zeroed.
// nq = dst_rows * 192 quads (768 cols / 4).
// ---------------------------------------------------------------------------
__global__ __launch_bounds__(256) void k_split(
    const float* __restrict__ src, unsigned short* __restrict__ hi,
    unsigned short* __restrict__ lo, int src_rows, int nq)
{
    const int idx = blockIdx.x * 256 + threadIdx.x;
    if (idx >= nq) return;
    const int c = idx / 192;
    const int kk = (idx % 192) * 4;
    unsigned short h[4] = {0, 0, 0, 0}, l[4] = {0, 0, 0, 0};
    if (c < src_rows) {
        const float4 w = *(const float4*)&src[(size_t)c * 768 + kk];
        const float wv[4] = {w.x, w.y, w.z, w.w};
#pragma unroll
        for (int j = 0; j < 4; ++j) {
            h[j] = f32_to_bf16_rne(wv[j]);
            l[j] = f32_to_bf16_rne(wv[j] - bf16_to_f32(h[j]));
        }
    }
    *(uint2*)&hi[(size_t)c * 768 + kk] = make_uint2(pck(h[0], h[1]), pck(h[2], h[3]));
    *(uint2*)&lo[(size_t)c * 768 + kk] = make_uint2(pck(l[0], l[1]), pck(l[2], l[3]));
}

// ---------------------------------------------------------------------------
// K1: logits[12544][256] = x @ W^T via bf16-split MFMA (hi*hi + hi*lo + lo*hi).
// BM=64, BN=128, BK=32; 4 waves (2M x 2N); wave tile 32x64 (2x4 frags).
// Verified conflict-free (round-2 SQ_LDS_BANK_CONFLICT = 0).
// ---------------------------------------------------------------------------
__global__ __launch_bounds__(256) void k_logits(
    const float* __restrict__ x, const unsigned short* __restrict__ Whi,
    const unsigned short* __restrict__ Wlo, float* __restrict__ logits)
{
    __shared__ unsigned short Ah[4][64][8], Alo[4][64][8];   // 8 KB
    __shared__ unsigned short Bh[8][64][8], Blo[8][64][8];   // 16 KB
    const int tid = threadIdx.x;
    const int lane = tid & 63;
    const int wid = tid >> 6;
    const int wm = wid & 1, wn = wid >> 1;
    const int row0 = blockIdx.x * 64;
    const int n0 = blockIdx.y * 128;

    f32x4 acc[2][4];
    const f32x4 z = {0.f, 0.f, 0.f, 0.f};
#pragma unroll
    for (int mi = 0; mi < 2; ++mi)
#pragma unroll
        for (int q = 0; q < 4; ++q) acc[mi][q] = z;

    const int ar = tid & 63;       // A: row within tile
    const int ap = tid >> 6;       // A: k-octet 0..3
    const int bc = tid >> 1;       // B: class within tile 0..127
    const int bkh = tid & 1;       // B: k-half 0..1

    for (int kc = 0; kc < 768; kc += 32) {
        __syncthreads();
        {   // A stage + on-the-fly bf16 split
            const float* src = &x[(size_t)(row0 + ar) * 768 + kc + ap * 8];
            const float4 v0 = *(const float4*)src;
            const float4 v1 = *(const float4*)(src + 4);
            const float av[8] = {v0.x, v0.y, v0.z, v0.w, v1.x, v1.y, v1.z, v1.w};
            unsigned short h[8], l[8];
#pragma unroll
            for (int j = 0; j < 8; ++j) {
                h[j] = f32_to_bf16_rne(av[j]);
                l[j] = f32_to_bf16_rne(av[j] - bf16_to_f32(h[j]));
            }
            const int m = ar >> 4, ci = ar & 15;
            *(uint4*)&Ah[m][ap * 16 + ci][0] =
                make_uint4(pck(h[0], h[1]), pck(h[2], h[3]), pck(h[4], h[5]), pck(h[6], h[7]));
            *(uint4*)&Alo[m][ap * 16 + ci][0] =
                make_uint4(pck(l[0], l[1]), pck(l[2], l[3]), pck(l[4], l[5]), pck(l[6], l[7]));
        }
        {   // B stage (already bf16): 1 class x 16 k per thread
            const size_t off = (size_t)(n0 + bc) * 768 + kc + bkh * 16;
            const uint4 h0 = *(const uint4*)&Whi[off];
            const uint4 h1 = *(const uint4*)&Whi[off + 8];
            const uint4 l0 = *(const uint4*)&Wlo[off];
            const uint4 l1 = *(const uint4*)&Wlo[off + 8];
            const int q = bc >> 4, ci = bc & 15;
            *(uint4*)&Bh[q][(2 * bkh) * 16 + ci][0] = h0;
            *(uint4*)&Bh[q][(2 * bkh + 1) * 16 + ci][0] = h1;
            *(uint4*)&Blo[q][(2 * bkh) * 16 + ci][0] = l0;
            *(uint4*)&Blo[q][(2 * bkh + 1) * 16 + ci][0] = l1;
        }
        __syncthreads();

        bf16x8 a_h[2], a_l[2];
#pragma unroll
        for (int mi = 0; mi < 2; ++mi) {
            a_h[mi] = *(const bf16x8*)&Ah[wm * 2 + mi][lane][0];
            a_l[mi] = *(const bf16x8*)&Alo[wm * 2 + mi][lane][0];
        }
#pragma unroll
        for (int q = 0; q < 4; ++q) {
            const bf16x8 bh = *(const bf16x8*)&Bh[wn * 4 + q][lane][0];
            const bf16x8 bl = *(const bf16x8*)&Blo[wn * 4 + q][lane][0];
#pragma unroll
            for (int mi = 0; mi < 2; ++mi) {
                acc[mi][q] = __builtin_amdgcn_mfma_f32_16x16x32_bf16(a_l[mi], bh, acc[mi][q], 0, 0, 0);
                acc[mi][q] = __builtin_amdgcn_mfma_f32_16x16x32_bf16(a_h[mi], bl, acc[mi][q], 0, 0, 0);
                acc[mi][q] = __builtin_amdgcn_mfma_f32_16x16x32_bf16(a_h[mi], bh, acc[mi][q], 0, 0, 0);
            }
        }
    }

#pragma unroll
    for (int mi = 0; mi < 2; ++mi)
#pragma unroll
        for (int q = 0; q < 4; ++q)
#pragma unroll
            for (int r = 0; r < 4; ++r) {
                const int row = row0 + wm * 32 + mi * 16 + (lane >> 4) * 4 + r;
                const int col = n0 + wn * 64 + q * 16 + (lane & 15);
                logits[(size_t)row * 256 + col] = acc[mi][q][r];
            }
}

// ---------------------------------------------------------------------------
// K1b: maxprob[row] = 1 / sum(exp(logit - max)). One wave per row.
// ---------------------------------------------------------------------------
__global__ __launch_bounds__(256) void k_softmax(
    const float* __restrict__ logits, const float* __restrict__ bfc,
    float* __restrict__ maxprob)
{
    const int row = blockIdx.x * 4 + (threadIdx.x >> 6);
    const int lane = threadIdx.x & 63;
    float v[4];
    float m = -1e30f;
#pragma unroll
    for (int j = 0; j < 4; ++j) {
        const int c = lane + j * 64;
        v[j] = (c < 200) ? (logits[(size_t)row * 256 + c] + bfc[c]) : -1e30f;
        m = fmaxf(m, v[j]);
    }
#pragma unroll
    for (int s = 32; s; s >>= 1) m = fmaxf(m, __shfl_xor(m, s, 64));
    float se = 0.f;
#pragma unroll
    for (int j = 0; j < 4; ++j) {
        const int c = lane + j * 64;
        if (c < 200) se += __expf(v[j] - m);
    }
#pragma unroll
    for (int s = 32; s; s >>= 1) se += __shfl_xor(se, s, 64);
    if (lane == 0) maxprob[row] = 1.0f / se;
}

// ---------------------------------------------------------------------------
// K2: part_logits + argmax -> sel  (unchanged, correct)
// ---------------------------------------------------------------------------
__global__ void k_sel(const float* __restrict__ maxprob,
                      const float* __restrict__ mask, int* __restrict__ sel)
{
    __shared__ float mp[784];
    __shared__ float pl[81];
    const int b = blockIdx.x, tid = threadIdx.x;
    for (int i = tid; i < 784; i += blockDim.x) mp[i] = maxprob[b * 784 + i];
    __syncthreads();
    if (tid < 81) {
        const int pr = tid / 9, pc = tid % 9;
        float s = 0.f;
        for (int ki = 0; ki < 8; ++ki) {
            const int y = pr * 3 - 2 + ki;
            if (y < 0 || y >= 28) continue;
            for (int kj = 0; kj < 8; ++kj) {
                const int xx = pc * 3 - 2 + kj;
                if (xx < 0 || xx >= 28) continue;
                s += mp[y * 28 + xx];
            }
        }
        pl[tid] = mask[b * 81 + tid] * (s * (1.f / 64.f));
    }
    __syncthreads();
    if (tid == 0) {
        float best = pl[0]; int bi = 0;
        for (int i = 1; i < 81; ++i) if (pl[i] > best) { best = pl[i]; bi = i; }
        sel[b] = bi;
    }
}

__device__ __forceinline__ void rcoef8(int o, int n, int& f0, int& f1, float& w)
{
    float s = (o + 0.5f) * ((float)n * 0.125f) - 0.5f;
    s = fminf(fmaxf(s, 0.f), (float)(n - 1));
    f0 = (int)s;
    w = s - (float)f0;
    f1 = f0 + 1; if (f1 > n - 1) f1 = n - 1;
}

// ---------------------------------------------------------------------------
// K3: fused build + ff GEMM.  grid = 16 b x 12 n-tiles of 64.
// Per K-chunk (32 ch): gather 8x8 window rows of x into W8 (zero-padded),
// compute bilinear A rows (seg l: identity; m: 6->8; s: 4->8), bf16-split
// into frag-major LDS, 3-term MFMA against pre-split Wcat.
// out[b, i, n0+col] = acc + bias.
// ---------------------------------------------------------------------------
__global__ __launch_bounds__(256) void k_ff(
    const float* __restrict__ x, const int* __restrict__ sel,
    const unsigned short* __restrict__ Whi2, const unsigned short* __restrict__ Wlo2,
    const float* __restrict__ bl, const float* __restrict__ bm,
    const float* __restrict__ bs_, float* __restrict__ out)
{
    __shared__ float W8[64][33];                               // 8.25 KB, pad->2-way max
    __shared__ unsigned short Ah[4][64][8], Alo[4][64][8];     // 8 KB
    __shared__ unsigned short Bh[4][64][8], Blo[4][64][8];     // 8 KB

    const int blk = blockIdx.x;
    const int b = blk / 12, t = blk % 12;
    const int n0 = t * 64;
    const int seg = (t < 3) ? 0 : ((t < 6) ? 1 : 2);
    const float* bias = (seg == 0) ? (bl + t * 64)
                      : (seg == 1) ? (bm + (t - 3) * 64)
                                   : (bs_ + (t - 6) * 64);
    const int s = sel[b];
    const int wy0 = (s / 9) * 3 - 2, wx0 = (s % 9) * 3 - 2;

    const int tid = threadIdx.x;
    const int lane = tid & 63;
    const int wid = tid >> 6, wmi = wid & 1, wn = wid >> 1;

    // gather mapping: window pos gp, k-octet ko
    const int gp = tid & 63;
    const int gy = wy0 + (gp >> 3), gx = wx0 + (gp & 7);
    const bool inb = (gy >= 0 && gy < 28 && gx >= 0 && gx < 28);
    const float* xsrc = x + ((size_t)b * 784 + (inb ? (gy * 28 + gx) : 0)) * 768;
    const int ko = (tid >> 6) * 8;

    // A-compute mapping: output row ai (same lanes), corner rows + weights
    const int ai = tid & 63;
    int r00, r01, r10, r11; float fx = 0.f, fy = 0.f;
    if (seg == 0) { r00 = r01 = r10 = r11 = ai; }
    else {
        const int nn = (seg == 1) ? 6 : 4, off = (seg == 1) ? 1 : 2;
        int f0y, f1y, f0x, f1x;
        rcoef8(ai >> 3, nn, f0y, f1y, fy);
        rcoef8(ai & 7, nn, f0x, f1x, fx);
        r00 = (off + f0y) * 8 + off + f0x;
        r01 = (off + f0y) * 8 + off + f1x;
        r10 = (off + f1y) * 8 + off + f0x;
        r11 = (off + f1y) * 8 + off + f1x;
    }

    // B staging mapping: class bc (0..63), k-octet kq (0..3)
    const int bc = tid >> 2, kq = tid & 3;
    const unsigned short* WhP = Whi2 + (size_t)(n0 + bc) * 768 + kq * 8;
    const unsigned short* WlP = Wlo2 + (size_t)(n0 + bc) * 768 + kq * 8;

    f32x4 acc[2][2];
    const f32x4 z = {0.f, 0.f, 0.f, 0.f};
#pragma unroll
    for (int mi = 0; mi < 2; ++mi)
#pragma unroll
        for (int q = 0; q < 2; ++q) acc[mi][q] = z;

    for (int kc = 0; kc < 768; kc += 32) {
        __syncthreads();
        {   // gather window chunk
            float v[8] = {0, 0, 0, 0, 0, 0, 0, 0};
            if (inb) {
                const float4 a0 = *(const float4*)(xsrc + kc + ko);
                const float4 a1 = *(const float4*)(xsrc + kc + ko + 4);
                v[0] = a0.x; v[1] = a0.y; v[2] = a0.z; v[3] = a0.w;
                v[4] = a1.x; v[5] = a1.y; v[6] = a1.z; v[7] = a1.w;
            }
#pragma unroll
            for (int j = 0; j < 8; ++j) W8[gp][ko + j] = v[j];
        }
        {   // B stage
            const uint4 h = *(const uint4*)(WhP + kc);
            const uint4 l = *(const uint4*)(WlP + kc);
            *(uint4*)&Bh[bc >> 4][kq * 16 + (bc & 15)][0] = h;
            *(uint4*)&Blo[bc >> 4][kq * 16 + (bc & 15)][0] = l;
        }
        __syncthreads();
        {   // A compute (bilinear) + bf16 split into frag-major LDS
            unsigned short h[8], l[8];
#pragma unroll
            for (int j = 0; j < 8; ++j) {
                const int k = ko + j;
                const float g00 = W8[r00][k], g01 = W8[r01][k];
                const float g10 = W8[r10][k], g11 = W8[r11][k];
                const float v0 = g00 + fx * (g01 - g00);
                const float v1 = g10 + fx * (g11 - g10);
                const float a = v0 + fy * (v1 - v0);
                h[j] = f32_to_bf16_rne(a);
                l[j] = f32_to_bf16_rne(a - bf16_to_f32(h[j]));
            }
            const int m = ai >> 4, ci = ai & 15, p2 = ko >> 3;
            *(uint4*)&Ah[m][p2 * 16 + ci][0] =
                make_uint4(pck(h[0], h[1]), pck(h[2], h[3]), pck(h[4], h[5]), pck(h[6], h[7]));
            *(uint4*)&Alo[m][p2 * 16 + ci][0] =
                make_uint4(pck(l[0], l[1]), pck(l[2], l[3]), pck(l[4], l[5]), pck(l[6], l[7]));
        }
        __syncthreads();

        bf16x8 a_h[2], a_l[2];
#pragma unroll
        for (int mi = 0; mi < 2; ++mi) {
            a_h[mi] = *(const bf16x8*)&Ah[wmi * 2 + mi][lane][0];
            a_l[mi] = *(const bf16x8*)&Alo[wmi * 2 + mi][lane][0];
        }
#pragma unroll
        for (int q = 0; q < 2; ++q) {
            const bf16x8 bh = *(const bf16x8*)&Bh[wn * 2 + q][lane][0];
            const bf16x8 bl2 = *(const bf16x8*)&Blo[wn * 2 + q][lane][0];
#pragma unroll
            for (int mi = 0; mi < 2; ++mi) {
                acc[mi][q] = __builtin_amdgcn_mfma_f32_16x16x32_bf16(a_l[mi], bh, acc[mi][q], 0, 0, 0);
                acc[mi][q] = __builtin_amdgcn_mfma_f32_16x16x32_bf16(a_h[mi], bl2, acc[mi][q], 0, 0, 0);
                acc[mi][q] = __builtin_amdgcn_mfma_f32_16x16x32_bf16(a_h[mi], bh, acc[mi][q], 0, 0, 0);
            }
        }
    }

#pragma unroll
    for (int mi = 0; mi < 2; ++mi)
#pragma unroll
        for (int q = 0; q < 2; ++q)
#pragma unroll
            for (int r = 0; r < 4; ++r) {
                const int row = wmi * 32 + mi * 16 + (lane >> 4) * 4 + r;
                const int col = wn * 32 + q * 16 + (lane & 15);
                out[((size_t)b * 64 + row) * 768 + n0 + col] = acc[mi][q][r] + bias[col];
            }
}

// ---------------------------------------------------------------------------
// K4: image_part gather + 128->224 bilinear. Unchanged.
// ---------------------------------------------------------------------------
__global__ __launch_bounds__(256) void k_image(
    const float* __restrict__ img, const int* __restrict__ sel,
    float* __restrict__ out)
{
    const int idx = blockIdx.x * 256 + threadIdx.x;
    if (idx >= 16 * 3 * 224 * 224) return;
    const int ox = idx % 224;
    int t = idx / 224;
    const int oy = t % 224; t /= 224;
    const int c = t % 3;
    const int b = t / 3;
    const int s = sel[b];
    const int ry0 = (s / 9) * 48 - 32, cx0 = (s % 9) * 48 - 32;

    float sy = (oy + 0.5f) * (128.f / 224.f) - 0.5f;
    sy = fminf(fmaxf(sy, 0.f), 127.f);
    const int fy0 = (int)sy; const float wy = sy - (float)fy0;
    const int fy1 = (fy0 < 127) ? fy0 + 1 : 127;

    float sx = (ox + 0.5f) * (128.f / 224.f) - 0.5f;
    sx = fminf(fmaxf(sx, 0.f), 127.f);
    const int fx0 = (int)sx; const float wx = sx - (float)fx0;
    const int fx1 = (fx0 < 127) ? fx0 + 1 : 127;

    const float* ib = img + ((size_t)b * 3 + c) * 448 * 448;
    auto rd = [&](int py, int px) -> float {
        const int r = ry0 + py, cc = cx0 + px;
        return (r >= 0 && r < 448 && cc >= 0 && cc < 448) ? ib[r * 448 + cc] : 0.f;
    };
    const float g00 = rd(fy0, fx0), g01 = rd(fy0, fx1);
    const float g10 = rd(fy1, fx0), g11 = rd(fy1, fx1);
    const float v0 = g00 + wx * (g01 - g00);
    const float v1 = g10 + wx * (g11 - g10);
    out[idx] = v0 + wy * (v1 - v0);
}

// ---------------------------------------------------------------------------
extern "C" void kernel_launch(void* const* d_in, const int* in_sizes, int n_in,
                              void* d_out, int out_size, void* d_ws, size_t ws_size,
                              hipStream_t stream)
{
    const float* x    = (const float*)d_in[0];
    const float* mask = (const float*)d_in[1];
    const float* img  = (const float*)d_in[2];
    const float* Wfc  = (const float*)d_in[3];
    const float* bfc  = (const float*)d_in[4];
    const float* Wl   = (const float*)d_in[5];
    const float* bl   = (const float*)d_in[6];
    const float* Wm   = (const float*)d_in[7];
    const float* bm   = (const float*)d_in[8];
    const float* Ws   = (const float*)d_in[9];
    const float* bs   = (const float*)d_in[10];
    float* out = (float*)d_out;

    char* ws = (char*)d_ws;
    float* maxprob      = (float*)ws;                        // 50176 B
    int*   sel          = (int*)(ws + 51200);
    unsigned short* Whi  = (unsigned short*)(ws + 65536);    // 256*768 bf16
    unsigned short* Wlo  = (unsigned short*)(ws + 65536 + 393216);
    unsigned short* Whi2 = (unsigned short*)(ws + 917504);   // 768*768 bf16 (Wcat)
    unsigned short* Wlo2 = (unsigned short*)(ws + 917504 + 1179648);
    float* logits = (float*)(ws + 3276800);                  // 12544*256 f32

    // weight splits (Wfc padded to 256 rows; Wcat = [Wl;Wm;Ws] rows 0..767)
    hipLaunchKernelGGL(k_split, dim3(192), dim3(256), 0, stream, Wfc, Whi, Wlo, 200, 256 * 192);
    hipLaunchKernelGGL(k_split, dim3(144), dim3(256), 0, stream, Wl, Whi2, Wlo2, 192, 192 * 192);
    hipLaunchKernelGGL(k_split, dim3(144), dim3(256), 0, stream,
                       Wm, Whi2 + (size_t)192 * 768, Wlo2 + (size_t)192 * 768, 192, 192 * 192);
    hipLaunchKernelGGL(k_split, dim3(288), dim3(256), 0, stream,
                       Ws, Whi2 + (size_t)384 * 768, Wlo2 + (size_t)384 * 768, 384, 384 * 192);

    hipLaunchKernelGGL(k_logits,  dim3(196, 2), dim3(256), 0, stream, x, Whi, Wlo, logits);
    hipLaunchKernelGGL(k_softmax, dim3(3136),   dim3(256), 0, stream, logits, bfc, maxprob);
    hipLaunchKernelGGL(k_sel,     dim3(16),     dim3(128), 0, stream, maxprob, mask, sel);
    hipLaunchKernelGGL(k_ff,      dim3(192),    dim3(256), 0, stream,
                       x, sel, Whi2, Wlo2, bl, bm, bs, out);
    hipLaunchKernelGGL(k_image,   dim3(9408),   dim3(256), 0, stream,
                       img, sel, out + 786432);
}